// Round 8
// baseline (180.507 us; speedup 1.0000x reference)
//
#include <hip/hip_runtime.h>
#include <math.h>

// Chamfer distance via MFMA, single fused kernel. pred/gt (4,8192,3) fp32.
// d(q,g) = s_q + s_g - 2 q.g as one K=16 fp16 MFMA (2-way fp16 split/coord,
// products exact in fp32 accum; layout verified R5-R7):
//   q k0-7 {xh,xh,xl,xl,yh,yh,yl,yl}  k8-15 {zh,zh,zl,zl, 1, 1,sh,sl}
//   t k0-7 {Xh,Xl,Xh,Xl,Yh,Yl,Yh,Yl}  k8-15 {Zh,Zl,Zh,Zl,sh,sl, 1, 1}  X=-2x
// R8: 4 B-frags/wave (1 a-load -> 4 indep MFMA chains), split LDS (lds0/lds1,
// conflict-free b128), last-block ticket reduction (ws 0xAA poison = +inf for
// uint atomicMin AND known ticket base 0xAAAAAAAA). Grid 1024 = 4 blocks/CU.

typedef _Float16 half8 __attribute__((ext_vector_type(8)));
typedef float f32x16 __attribute__((ext_vector_type(16)));

#define NPTS   8192
#define CLOUD  32768              // 4 batches * 8192
#define NQ_TOT 65536              // 2 dirs * CLOUD
#define TT     1024               // targets per block (32 KB LDS)
#define GRID   1024
#define POISON 0xAAAAAAAAu

__device__ __forceinline__ void split2(float v, _Float16& h, _Float16& l) {
  h = (_Float16)v; l = (_Float16)(v - (float)h);
}

__device__ __forceinline__ float min_fold(float m, const f32x16& d) {
  float a = fminf(fminf(d[0], d[1]), d[2]);
  float b = fminf(fminf(d[3], d[4]), d[5]);
  float c = fminf(fminf(d[6], d[7]), d[8]);
  float e = fminf(fminf(d[9], d[10]), d[11]);
  float f = fminf(fminf(d[12], d[13]), d[14]);
  float g = fminf(fminf(a, b), c);
  float h = fminf(fminf(e, f), d[15]);
  return fminf(m, fminf(g, h));
}

__global__ __launch_bounds__(256, 4) void chamfer_fused(
    const float* __restrict__ pred, const float* __restrict__ gt,
    unsigned int* __restrict__ minbits, unsigned int* __restrict__ ticket,
    float* __restrict__ out) {
  __shared__ __align__(16) half8 lds0[TT];   // k-slots 0-7 rows
  __shared__ __align__(16) half8 lds1[TT];   // k-slots 8-15 rows
  __shared__ unsigned int s_last;
  __shared__ float wsum[4];

  int bid = blockIdx.x;
  int tc   = bid & 7;              // target chunk [0,8)
  int qblk = (bid >> 3) & 15;      // query block of 512 [0,16)
  int b    = (bid >> 7) & 3;       // batch
  int dir  = bid >> 9;             // 0: q=pred t=gt ; 1: q=gt t=pred
  const float* qsrc = dir ? gt : pred;
  const float* tsrc = dir ? pred : gt;
  int t = threadIdx.x, lane = t & 63, wave = t >> 6;

  // ---- load this wave's 4x32 queries (broadcast within half-waves) ----
  const float* qb = qsrc + (size_t)(b * NPTS + qblk * 512 + wave * 128) * 3;
  float qx[4], qy[4], qz[4];
  #pragma unroll
  for (int h = 0; h < 4; ++h) {
    int qi = h * 32 + (lane & 31);
    qx[h] = qb[3 * qi]; qy[h] = qb[3 * qi + 1]; qz[h] = qb[3 * qi + 2];
  }

  // ---- stage + pack 1024 targets into split LDS ----
  const float* tb = tsrc + (size_t)(b * NPTS + tc * TT) * 3;
  for (int k = t; k < TT; k += 256) {
    float x = tb[3 * k], y = tb[3 * k + 1], z = tb[3 * k + 2];
    float s = x * x + y * y + z * z;
    _Float16 xh, xl, yh, yl, zh, zl, sh, sl;
    split2(x, xh, xl); split2(y, yh, yl); split2(z, zh, zl); split2(s, sh, sl);
    _Float16 Xh = (_Float16)(-2.f * (float)xh), Xl = (_Float16)(-2.f * (float)xl);
    _Float16 Yh = (_Float16)(-2.f * (float)yh), Yl = (_Float16)(-2.f * (float)yl);
    _Float16 Zh = (_Float16)(-2.f * (float)zh), Zl = (_Float16)(-2.f * (float)zl);
    _Float16 one = (_Float16)1.0f;
    lds0[k] = (half8){Xh, Xl, Xh, Xl, Yh, Yl, Yh, Yl};
    lds1[k] = (half8){Zh, Zl, Zh, Zl, sh, sl, one, one};
  }

  // ---- build 4 query B-frags in registers ----
  half8 bq[4];
  #pragma unroll
  for (int h = 0; h < 4; ++h) {
    float s = qx[h] * qx[h] + qy[h] * qy[h] + qz[h] * qz[h];
    _Float16 xh, xl, yh, yl, zh, zl, sh, sl;
    split2(qx[h], xh, xl); split2(qy[h], yh, yl); split2(qz[h], zh, zl); split2(s, sh, sl);
    _Float16 one = (_Float16)1.0f;
    bq[h] = (lane < 32) ? (half8){xh, xh, xl, xl, yh, yh, yl, yl}
                        : (half8){zh, zh, zl, zl, one, one, sh, sl};
  }
  __syncthreads();

  // ---- main loop: 1 ds_read_b128 -> 4 independent MFMA chains ----
  const half8* abase = (lane < 32) ? &lds0[lane & 31] : &lds1[lane & 31];
  float m0 = INFINITY, m1 = INFINITY, m2 = INFINITY, m3 = INFINITY;
  f32x16 zero = {};
  #pragma unroll 2
  for (int g = 0; g < TT / 32; ++g) {
    half8 a = abase[g * 32];
    f32x16 d0 = __builtin_amdgcn_mfma_f32_32x32x16_f16(a, bq[0], zero, 0, 0, 0);
    f32x16 d1 = __builtin_amdgcn_mfma_f32_32x32x16_f16(a, bq[1], zero, 0, 0, 0);
    f32x16 d2 = __builtin_amdgcn_mfma_f32_32x32x16_f16(a, bq[2], zero, 0, 0, 0);
    f32x16 d3 = __builtin_amdgcn_mfma_f32_32x32x16_f16(a, bq[3], zero, 0, 0, 0);
    m0 = min_fold(m0, d0);
    m1 = min_fold(m1, d1);
    m2 = min_fold(m2, d2);
    m3 = min_fold(m3, d3);
  }
  m0 = fminf(m0, __shfl_xor(m0, 32, 64));
  m1 = fminf(m1, __shfl_xor(m1, 32, 64));
  m2 = fminf(m2, __shfl_xor(m2, 32, 64));
  m3 = fminf(m3, __shfl_xor(m3, 32, 64));

  if (lane < 32) {
    size_t qi = (size_t)dir * CLOUD + b * NPTS + qblk * 512 + wave * 128 + (lane & 31);
    atomicMin(&minbits[qi],      __float_as_uint(fmaxf(m0, 0.f)));
    atomicMin(&minbits[qi + 32], __float_as_uint(fmaxf(m1, 0.f)));
    atomicMin(&minbits[qi + 64], __float_as_uint(fmaxf(m2, 0.f)));
    atomicMin(&minbits[qi + 96], __float_as_uint(fmaxf(m3, 0.f)));
  }

  // ---- last-block reduction (ticket base = ws poison 0xAAAAAAAA) ----
  __threadfence();
  if (t == 0) {
    unsigned int tk = atomicAdd(ticket, 1u);
    s_last = (tk - POISON == GRID - 1u) ? 1u : 0u;
  }
  __syncthreads();
  if (!s_last) return;

  __threadfence();
  float acc = 0.f;
  for (int i = t; i < NQ_TOT; i += 256) {
    unsigned int v = __hip_atomic_load(&minbits[i], __ATOMIC_RELAXED,
                                       __HIP_MEMORY_SCOPE_AGENT);
    acc += __uint_as_float(v);
  }
  acc *= (1.0f / 32768.0f);
  #pragma unroll
  for (int off = 32; off > 0; off >>= 1) acc += __shfl_down(acc, off, 64);
  if ((t & 63) == 0) wsum[t >> 6] = acc;
  __syncthreads();
  if (t == 0) out[0] = wsum[0] + wsum[1] + wsum[2] + wsum[3];
}

extern "C" void kernel_launch(void* const* d_in, const int* in_sizes, int n_in,
                              void* d_out, int out_size, void* d_ws, size_t ws_size,
                              hipStream_t stream) {
  const float* pred = (const float*)d_in[0];
  const float* gt   = (const float*)d_in[1];
  float* out = (float*)d_out;
  unsigned int* minbits = (unsigned int*)d_ws;               // 256 KB, 0xAA = +inf
  unsigned int* ticket  = (unsigned int*)d_ws + NQ_TOT;      // poisoned 0xAAAAAAAA

  chamfer_fused<<<GRID, 256, 0, stream>>>(pred, gt, minbits, ticket, out);
}